// Round 15
// baseline (3788.420 us; speedup 1.0000x reference)
//
#include <hip/hip_runtime.h>
#include <math.h>

#define NPTS 16384
#define NCTR 1024
#define BATCH 8
#define NCELL 512   // 8x8x8 Morton cells
#define NCONS 240   // consumer blocks in the mega kernel
#define GRID_MEGA (BATCH + NCONS)

typedef unsigned long long u64;
typedef unsigned int u32;

// Bit-exact squared distance matching numpy: ((dx*dx + dy*dy) + dz*dz),
// each op individually IEEE-rounded (no FMA contraction).
__device__ __forceinline__ float sq_dist(float x, float y, float z,
                                         float cx, float cy, float cz) {
  float dx = __fsub_rn(x, cx);
  float dy = __fsub_rn(y, cy);
  float dz = __fsub_rn(z, cz);
  return __fadd_rn(__fadd_rn(__fmul_rn(dx, dx), __fmul_rn(dy, dy)), __fmul_rn(dz, dz));
}

__device__ __forceinline__ float silu_f(float x) {
  return x / (1.0f + __expf(-x));
}

__device__ __forceinline__ u64 kmax(u64 a, u64 b) { return a > b ? a : b; }

__device__ __forceinline__ int morton_cell(float x, float y, float z) {
  int mx = min(7, max(0, (int)(x * 8.0f)));
  int my = min(7, max(0, (int)(y * 8.0f)));
  int mz = min(7, max(0, (int)(z * 8.0f)));
  int m = 0;
#pragma unroll
  for (int k = 0; k < 3; ++k) {
    m |= ((mx >> k) & 1) << (3 * k + 2);
    m |= ((my >> k) & 1) << (3 * k + 1);
    m |= ((mz >> k) & 1) << (3 * k + 0);
  }
  return m;
}

// ---------------------------------------------------------------------------
// Kernel 0: DETERMINISTIC Morton counting sort, one block per batch.
// ---------------------------------------------------------------------------
__global__ __launch_bounds__(1024) void sort_kernel(
    const float* __restrict__ xyz, float* __restrict__ sxg,
    float* __restrict__ syg, float* __restrict__ szg, int* __restrict__ sog) {
  const int b = blockIdx.x, t = threadIdx.x;
  const float* X = xyz + (size_t)b * 3 * NPTS;
  const float* Y = X + NPTS;
  const float* Z = X + 2 * NPTS;
  __shared__ int cnt[NCELL];
  __shared__ int off[NCELL];
  __shared__ int start[NCELL];
  __shared__ int so_l[NPTS];  // 64 KB
  for (int e = t; e < NCELL; e += 1024) cnt[e] = 0;
  __syncthreads();
#pragma unroll
  for (int j = 0; j < 16; ++j) {
    const int n = t + (j << 10);
    atomicAdd(&cnt[morton_cell(X[n], Y[n], Z[n])], 1);
  }
  __syncthreads();
  if (t < NCELL) off[t] = cnt[t];
  __syncthreads();
  for (int d = 1; d < NCELL; d <<= 1) {  // Hillis-Steele inclusive scan
    int v = 0;
    if (t < NCELL) { v = off[t]; if (t >= d) v += off[t - d]; }
    __syncthreads();
    if (t < NCELL) off[t] = v;
    __syncthreads();
  }
  if (t < NCELL) { off[t] -= cnt[t]; start[t] = off[t]; }
  __syncthreads();
  // phase A: ORDERED scatter in 16 rounds -> nearly-sorted cell contents
  for (int j = 0; j < 16; ++j) {
    const int n = t + (j << 10);
    const int pos = atomicAdd(&off[morton_cell(X[n], Y[n], Z[n])], 1);
    so_l[pos] = n;
    __syncthreads();
  }
  // phase B: deterministic intra-cell order (ascending orig index)
  if (t < NCELL) {
    const int s0 = start[t], k = cnt[t];
    for (int i2 = 1; i2 < k; ++i2) {
      const int key = so_l[s0 + i2];
      int j2 = i2 - 1;
      while (j2 >= 0 && so_l[s0 + j2] > key) {
        so_l[s0 + j2 + 1] = so_l[s0 + j2];
        --j2;
      }
      so_l[s0 + j2 + 1] = key;
    }
  }
  __syncthreads();
  // phase C: deterministic rebuild
  float* sx = sxg + (size_t)b * NPTS;
  float* sy = syg + (size_t)b * NPTS;
  float* sz = szg + (size_t)b * NPTS;
  int* so = sog + (size_t)b * NPTS;
#pragma unroll
  for (int j = 0; j < 16; ++j) {
    const int pos = t + (j << 10);
    const int n = so_l[pos];
    so[pos] = n;
    sx[pos] = X[n];
    sy[pos] = Y[n];
    sz[pos] = Z[n];
  }
}

// ---------------------------------------------------------------------------
// Kernel 2b: weight transpose + progress zeroing (runs before mega kernel).
// ---------------------------------------------------------------------------
__global__ __launch_bounds__(256) void transpose_w_kernel(
    const float* __restrict__ w0, const float* __restrict__ w1,
    const float* __restrict__ w2, float* __restrict__ wt0,
    float* __restrict__ wt1, float* __restrict__ wt2,
    u32* __restrict__ progress) {
  const int t0 = blockIdx.x * 256 + threadIdx.x;
  if (t0 < BATCH) progress[t0] = 0u;  // re-zero each graph replay
  const int stride = gridDim.x * 256;
  for (int e = t0; e < 64 * 67; e += stride) {
    int o = e / 67, c = e - o * 67;
    wt0[c * 64 + o] = w0[e];
  }
  for (int e = t0; e < 128 * 64; e += stride) {
    int o = e >> 6, c = e & 63;
    wt1[c * 128 + o] = w1[e];
  }
  for (int e = t0; e < 256 * 128; e += stride) {
    int o = e >> 7, c = e & 127;
    wt2[c * 256 + o] = w2[e];
  }
}

// ---------------------------------------------------------------------------
// Kernel 2c: points transpose [B][64][N] -> [B][N][64]. Kills the 16x gather
// transaction amplification measured in R13's mega-kernel PMC (1.65GB fetch).
// ---------------------------------------------------------------------------
__global__ __launch_bounds__(256) void transpose_p_kernel(
    const float* __restrict__ points, float* __restrict__ points_t) {
  __shared__ float tile[64 * 65];
  const int b = blockIdx.y;
  const int n0 = blockIdx.x * 64;
  const int t = threadIdx.x;
  const float* src = points + (size_t)b * 64 * NPTS;
  float* dst = points_t + (size_t)b * NPTS * 64;
#pragma unroll
  for (int i = 0; i < 16; ++i) {
    const int e = t + (i << 8);
    const int c = e >> 6, ni = e & 63;
    tile[c * 65 + ni] = src[(size_t)c * NPTS + n0 + ni];  // coalesced read
  }
  __syncthreads();
#pragma unroll
  for (int i = 0; i < 16; ++i) {
    const int f = t + (i << 8);
    const int n = f >> 6, c = f & 63;
    dst[(size_t)(n0 + n) * 64 + c] = tile[c * 65 + n];    // coalesced write
  }
}

// ---------------------------------------------------------------------------
// MEGA KERNEL v2 (cooperative, 248 blocks x 1024 thr, 1 block/CU):
// R13 structure (passed, bit-exact) + R14's COALESCED points_t gather — the
// one change that removes the 1.12GB gather amplification that made R13
// consumer-traffic-bound (3.4ms = 1.65GB / 484GB/s).
//  blocks 0..7   = PRODUCER: frozen R7 fps; publishes 64-centroid chunks
//                  (wave-0 store + RELEASE/AGENT progress[b]).
//  blocks 8..247 = CONSUMER: items j (s-major); t0 spins ACQUIRE/AGENT;
//                  wave-0 ballq -> jidx; coalesced gather from points_t;
//                  1024-thread 3-layer MLP, global-direct weights (L2-hot
//                  once the gather stream stops thrashing); identical
//                  per-(o,kg) FMA c-order as serial -> bit-exact.
// ---------------------------------------------------------------------------
#define CH_LIST(F) \
  F(0,a0)  F(1,a1)  F(2,a2)  F(3,a3)  F(4,a0)  F(5,a1)  F(6,a2)  F(7,a3)  \
  F(8,a0)  F(9,a1)  F(10,a2) F(11,a3) F(12,a0) F(13,a1) F(14,a2) F(15,a3)

union __align__(16) MegaSmem {
  struct {
    float sxy[2 * NPTS];   // 128 KB interleaved sorted x,y
    u64 slot[3][2];
    float s_zw[3][16];
    int fps_lds[NCTR];
  } p;
  struct {
    float A0[67 * 36];     // gathered input [c][k]
    float A1[64 * 36];     // layer0 out [o][k]; doubles as P[256*9]
    float A2[128 * 36];    // layer1 out [o][k]
    int jidx[32];
    float ctr[3];
  } c;
};

__global__ __launch_bounds__(1024)
void mega_kernel(const float* __restrict__ xyz, const float* __restrict__ points_t,
                 const float* __restrict__ sxg, const float* __restrict__ syg,
                 const float* __restrict__ szg, const int* __restrict__ sog,
                 int* __restrict__ fps_g, u32* __restrict__ progress,
                 const float* __restrict__ wt0, const float* __restrict__ b0,
                 const float* __restrict__ wt1, const float* __restrict__ b1,
                 const float* __restrict__ wt2, const float* __restrict__ b2,
                 float* __restrict__ out) {
  __shared__ MegaSmem sm;
  const int t = threadIdx.x;

  if (blockIdx.x < BATCH) {
    // ============================ PRODUCER (fps) ============================
    const int b = blockIdx.x;
    const int w = t >> 6, lane = t & 63;
    const float* X = xyz + (size_t)b * 3 * NPTS;
    const float* Y = X + NPTS;
    const float* Z = X + 2 * NPTS;
    const float* SX = sxg + (size_t)b * NPTS;
    const float* SY = syg + (size_t)b * NPTS;
    const float* SZ = szg + (size_t)b * NPTS;
    const int* SO = sog + (size_t)b * NPTS;

#define DECL_CH(c, acc) float z##c, d##c; u32 lo##c;
    CH_LIST(DECL_CH)
#undef DECL_CH

    const int wbase = (w << 6) + lane;  // INTERLEAVED mapping base

    float bmnx = __builtin_inff(), bmxx = -__builtin_inff();
    float bmny = __builtin_inff(), bmxy = -__builtin_inff();
    float bmnz = __builtin_inff(), bmxz = -__builtin_inff();

#define INIT_CH(c, acc)                                         \
    {                                                           \
      const int p = ((c) << 10) + wbase;                        \
      const float xv = SX[p], yv = SY[p], zv = SZ[p];           \
      sm.p.sxy[2 * p] = xv; sm.p.sxy[2 * p + 1] = yv;           \
      z##c = zv;                                                \
      const int o = SO[p];                                      \
      lo##c = ((u32)(16383 - o) << 14) | (u32)p;                \
      d##c = __builtin_inff();                                  \
      float mnx = xv, mxx = xv, mny = yv, mxy = yv;             \
      float mnz = zv, mxz = zv;                                 \
      _Pragma("unroll")                                         \
      for (int off = 32; off >= 1; off >>= 1) {                 \
        mnx = fminf(mnx, __shfl_xor(mnx, off));                 \
        mxx = fmaxf(mxx, __shfl_xor(mxx, off));                 \
        mny = fminf(mny, __shfl_xor(mny, off));                 \
        mxy = fmaxf(mxy, __shfl_xor(mxy, off));                 \
        mnz = fminf(mnz, __shfl_xor(mnz, off));                 \
        mxz = fmaxf(mxz, __shfl_xor(mxz, off));                 \
      }                                                         \
      if (lane == c) {                                          \
        bmnx = mnx; bmxx = mxx; bmny = mny;                     \
        bmxy = mxy; bmnz = mnz; bmxz = mxz;                     \
      }                                                         \
    }
    CH_LIST(INIT_CH)
#undef INIT_CH

#define PIN_CH(c, acc) asm volatile("" : "+v"(z##c));
    CH_LIST(PIN_CH)
#undef PIN_CH

    if (t < 6) sm.p.slot[t / 2][t & 1] = 0ull;
    if (t == 0) sm.p.fps_lds[0] = 0;
    __syncthreads();  // LDS staging complete, slots zeroed

    float cx = X[0], cy = Y[0], cz = Z[0];
    float gd = __builtin_inff();
    u64 gkey = 0ull;
    float gz = 0.0f;
    int wmaxch = 0;

#define MK(c) ((((u64)__float_as_uint(d##c)) << 32) | (u64)lo##c)
#define KSEL(ka, za, kb, zb, ko, zo)          \
    {                                         \
      const u64 ka_ = (ka), kb_ = (kb);       \
      const bool g_ = ka_ > kb_;              \
      ko = g_ ? ka_ : kb_;                    \
      zo = g_ ? (za) : (zb);                  \
    }

    for (int i = 1; i < NCTR; ++i) {
      const float ux = fmaxf(fmaxf(__fsub_rn(bmnx, cx), __fsub_rn(cx, bmxx)), 0.0f);
      const float uy = fmaxf(fmaxf(__fsub_rn(bmny, cy), __fsub_rn(cy, bmxy)), 0.0f);
      const float uz = fmaxf(fmaxf(__fsub_rn(bmnz, cz), __fsub_rn(cz, bmxz)), 0.0f);
      const float lb = __fadd_rn(__fadd_rn(__fmul_rn(ux, ux), __fmul_rn(uy, uy)),
                                 __fmul_rn(uz, uz));
      const u32 mask = (u32)__ballot(!(__fmul_rn(lb, 0.9999f) >= gd));
      if (mask != 0u) {
        if (__builtin_popcount(mask) >= 6) {
#define UPDU_CH(c, acc)                                                    \
          {                                                                \
            const float2 xy =                                              \
                *(const float2*)(sm.p.sxy + 2 * (((c) << 10) + wbase));    \
            const float dd = sq_dist(xy.x, xy.y, z##c, cx, cy, cz);        \
            d##c = fminf(d##c, dd);                                        \
          }
          CH_LIST(UPDU_CH)
#undef UPDU_CH
        } else {
#define UPDG_CH(c, acc)                                                    \
          if (mask & (1u << (c))) {                                        \
            const float2 xy =                                              \
                *(const float2*)(sm.p.sxy + 2 * (((c) << 10) + wbase));    \
            float dd = sq_dist(xy.x, xy.y, z##c, cx, cy, cz);              \
            asm volatile("" : "+v"(dd));                                   \
            d##c = fminf(d##c, dd);                                        \
          }
          CH_LIST(UPDG_CH)
#undef UPDG_CH
        }
        if ((mask >> wmaxch) & 1u) {
          u64 m0, m1, m2, m3, m4, m5, m6, m7, q0, q1, q2, q3, h0, h1, kk;
          float n0, n1, n2, n3, n4, n5, n6, n7, r0, r1, r2, r3, e0, e1, bz;
          KSEL(MK(0), z0, MK(1), z1, m0, n0)    KSEL(MK(2), z2, MK(3), z3, m1, n1)
          KSEL(MK(4), z4, MK(5), z5, m2, n2)    KSEL(MK(6), z6, MK(7), z7, m3, n3)
          KSEL(MK(8), z8, MK(9), z9, m4, n4)    KSEL(MK(10), z10, MK(11), z11, m5, n5)
          KSEL(MK(12), z12, MK(13), z13, m6, n6) KSEL(MK(14), z14, MK(15), z15, m7, n7)
          KSEL(m0, n0, m1, n1, q0, r0)  KSEL(m2, n2, m3, n3, q1, r1)
          KSEL(m4, n4, m5, n5, q2, r2)  KSEL(m6, n6, m7, n7, q3, r3)
          KSEL(q0, r0, q1, r1, h0, e0)  KSEL(q2, r2, q3, r3, h1, e1)
          KSEL(h0, e0, h1, e1, kk, bz)
#pragma unroll
          for (int off = 32; off >= 1; off >>= 1) {
            const u64 ok = __shfl_xor(kk, off);
            const float oz = __shfl_xor(bz, off);
            const bool g_ = ok > kk;
            kk = g_ ? ok : kk;
            bz = g_ ? oz : bz;
          }
          gkey = kk;
          gz = bz;
          gd = __uint_as_float((u32)(gkey >> 32));
          wmaxch = (int)(((u32)gkey >> 10) & 15u);
        }
      }
      const int si = i % 3;
      if (lane == 0) {
        sm.p.s_zw[si][w] = gz;
        atomicMax(&sm.p.slot[si][w & 1], gkey);
      }
      if (t == 0) {
        const int nsi = si == 2 ? 0 : si + 1;
        sm.p.slot[nsi][0] = 0ull;
        sm.p.slot[nsi][1] = 0ull;
      }
      __syncthreads();  // the ONLY barrier per step

      const u64 m = kmax(sm.p.slot[si][0], sm.p.slot[si][1]);
      const u32 lowb = (u32)m;
      const int pw = (int)(lowb & 0x3FFFu);
      if (t == 0) sm.p.fps_lds[i] = 16383 - (int)((lowb >> 14) & 0x3FFFu);

      const int pu = __builtin_amdgcn_readfirstlane(pw);
      const float2 cxy = *(const float2*)(sm.p.sxy + 2 * pu);
      cx = cxy.x;
      cy = cxy.y;
      cz = sm.p.s_zw[si][(pu >> 6) & 15];

      // publish a 64-centroid chunk (wave 0; RELEASE orders stores first)
      if (w == 0 && (i & 63) == 63) {
        const int base0 = i - 63;
        fps_g[b * NCTR + base0 + lane] = sm.p.fps_lds[base0 + lane];
        if (lane == 0)
          __hip_atomic_store(&progress[b], (u32)(i + 1), __ATOMIC_RELEASE,
                             __HIP_MEMORY_SCOPE_AGENT);
      }
    }
#undef MK
#undef KSEL
    return;
  }

  // ============================ CONSUMER (ballq+mlp) ========================
  const int cb = blockIdx.x - BATCH;  // 0..NCONS-1
  for (int j = cb; j < BATCH * NCTR; j += NCONS) {
    const int s = j >> 3, b_ = j & 7;  // s-major: early s ready first
    if (t == 0) {
      while (__hip_atomic_load(&progress[b_], __ATOMIC_ACQUIRE,
                               __HIP_MEMORY_SCOPE_AGENT) < (u32)(s + 1))
        __builtin_amdgcn_s_sleep(64);
    }
    __syncthreads();

    const float* X = xyz + (size_t)b_ * 3 * NPTS;
    const float* Y = X + NPTS;
    const float* Z = X + 2 * NPTS;

    // ball query by wave 0 -> LDS jidx + ctr (identical logic to ballq_kernel)
    if (t < 64) {
      const int lane = t;
      const int c = fps_g[b_ * NCTR + s];
      const float cx = X[c], cy = Y[c], cz = Z[c];
      if (lane == 0) { sm.c.ctr[0] = cx; sm.c.ctr[1] = cy; sm.c.ctr[2] = cz; }
      const float R2 = 0.04f;
      int cnt = 0, first = -1;
      for (int base = 0; base < NPTS; base += 64) {
        const int jj = base + lane;
        const float d = sq_dist(X[jj], Y[jj], Z[jj], cx, cy, cz);
        const bool inb = !(d > R2);
        const unsigned long long mm = __ballot(inb);
        if (first < 0 && mm != 0ull) first = base + __ffsll(mm) - 1;
        if (inb) {
          const int pos = cnt + __popcll(mm & ((1ull << lane) - 1ull));
          if (pos < 32) sm.c.jidx[pos] = jj;
        }
        cnt += __popcll(mm);
        if (cnt >= 32) break;
      }
      for (int k2 = cnt + lane; k2 < 32; k2 += 64) sm.c.jidx[k2] = first;
    }
    __syncthreads();

    // gather A0: xyz rows + COALESCED points_t rows (256B/sample segment)
    if (t < 96) {
      const int c = t >> 5, k = t & 31;
      sm.c.A0[c * 36 + k] =
          xyz[((size_t)b_ * 3 + c) * NPTS + sm.c.jidx[k]] - sm.c.ctr[c];
    }
#pragma unroll
    for (int pass = 0; pass < 2; ++pass) {
      const int e = t + (pass << 10);
      const int c = e & 63, k = e >> 6;
      sm.c.A0[(c + 3) * 36 + k] =
          points_t[((size_t)b_ * NPTS + sm.c.jidx[k]) * 64 + c];
    }
    __syncthreads();

    // layer 0 (67 -> 64): 512 threads, o = t&63, kg = t>>6
    if (t < 512) {
      const int o = t & 63, k0 = (t >> 6) * 4;
      const float bb = b0[o];
      float a0 = 0.f, a1 = 0.f, a2 = 0.f, a3 = 0.f;
      for (int c = 0; c < 67; ++c) {
        const float4 a = *(const float4*)(sm.c.A0 + c * 36 + k0);
        const float wv = wt0[c * 64 + o];  // global, L2-hot
        a0 = fmaf(a.x, wv, a0);
        a1 = fmaf(a.y, wv, a1);
        a2 = fmaf(a.z, wv, a2);
        a3 = fmaf(a.w, wv, a3);
      }
      float4 r;
      r.x = silu_f(a0 + bb);
      r.y = silu_f(a1 + bb);
      r.z = silu_f(a2 + bb);
      r.w = silu_f(a3 + bb);
      *(float4*)(sm.c.A1 + o * 36 + k0) = r;
    }
    __syncthreads();

    // layer 1 (64 -> 128): 1024 threads, o = t&127, kg = t>>7
    {
      const int o = t & 127, k0 = (t >> 7) * 4;
      const float bb = b1[o];
      float a0 = 0.f, a1 = 0.f, a2 = 0.f, a3 = 0.f;
      for (int c = 0; c < 64; ++c) {
        const float4 a = *(const float4*)(sm.c.A1 + c * 36 + k0);
        const float wv = wt1[c * 128 + o];
        a0 = fmaf(a.x, wv, a0);
        a1 = fmaf(a.y, wv, a1);
        a2 = fmaf(a.z, wv, a2);
        a3 = fmaf(a.w, wv, a3);
      }
      float4 r;
      r.x = silu_f(a0 + bb);
      r.y = silu_f(a1 + bb);
      r.z = silu_f(a2 + bb);
      r.w = silu_f(a3 + bb);
      *(float4*)(sm.c.A2 + o * 36 + k0) = r;
    }
    __syncthreads();

    // layer 2 (128 -> 256): each thread does o and o+128; P overlays A1
    {
      float* P = sm.c.A1;  // [256][9] = 2304 floats, exactly A1's size
      const int o = t & 127, kg = t >> 7, k0 = kg * 4;
#pragma unroll
      for (int half = 0; half < 2; ++half) {
        const int oo = half * 128 + o;
        const float bb = b2[oo];
        float a0 = 0.f, a1 = 0.f, a2 = 0.f, a3 = 0.f;
        for (int c = 0; c < 128; ++c) {
          const float4 a = *(const float4*)(sm.c.A2 + c * 36 + k0);
          const float wv = wt2[c * 256 + oo];
          a0 = fmaf(a.x, wv, a0);
          a1 = fmaf(a.y, wv, a1);
          a2 = fmaf(a.z, wv, a2);
          a3 = fmaf(a.w, wv, a3);
        }
        const float sum = silu_f(a0 + bb) + silu_f(a1 + bb) +
                          silu_f(a2 + bb) + silu_f(a3 + bb);
        P[oo * 9 + kg] = sum;
      }
    }
    __syncthreads();

    // mean over the 8 k-groups (same q-order as serial) + output
    if (t < 256) {
      const float* P = sm.c.A1;
      float tot = 0.f;
#pragma unroll
      for (int q = 0; q < 8; ++q) tot += P[t * 9 + q];
      out[((size_t)b_ * 256 + t) * NCTR + s] = tot * (1.0f / 32.0f);
    }
    __syncthreads();  // LDS reuse safe for next item
  }
}

// ---------------------------------------------------------------------------
// FALLBACK PATH (if cooperative launch rejected): R14 serial pipeline.
// ---------------------------------------------------------------------------
__global__ __launch_bounds__(1024)
void fps_kernel(const float* __restrict__ xyz, const float* __restrict__ sxg,
                const float* __restrict__ syg, const float* __restrict__ szg,
                const int* __restrict__ sog, int* __restrict__ fps_idx) {
  const int b = blockIdx.x;
  const int t = threadIdx.x;
  const int w = t >> 6, lane = t & 63;
  const float* X = xyz + (size_t)b * 3 * NPTS;
  const float* Y = X + NPTS;
  const float* Z = X + 2 * NPTS;
  const float* SX = sxg + (size_t)b * NPTS;
  const float* SY = syg + (size_t)b * NPTS;
  const float* SZ = szg + (size_t)b * NPTS;
  const int* SO = sog + (size_t)b * NPTS;

  __shared__ float sxy[2 * NPTS];
  __shared__ __align__(16) u64 slot[3][2];
  __shared__ float s_zw[3][16];
  __shared__ int fps_lds[NCTR];

#define DECL_CH(c, acc) float z##c, d##c; u32 lo##c;
  CH_LIST(DECL_CH)
#undef DECL_CH

  const int wbase = (w << 6) + lane;

  float bmnx = __builtin_inff(), bmxx = -__builtin_inff();
  float bmny = __builtin_inff(), bmxy = -__builtin_inff();
  float bmnz = __builtin_inff(), bmxz = -__builtin_inff();

#define INIT_CH(c, acc)                                         \
  {                                                             \
    const int p = ((c) << 10) + wbase;                          \
    const float xv = SX[p], yv = SY[p], zv = SZ[p];             \
    sxy[2 * p] = xv; sxy[2 * p + 1] = yv;                       \
    z##c = zv;                                                  \
    const int o = SO[p];                                        \
    lo##c = ((u32)(16383 - o) << 14) | (u32)p;                  \
    d##c = __builtin_inff();                                    \
    float mnx = xv, mxx = xv, mny = yv, mxy = yv;               \
    float mnz = zv, mxz = zv;                                   \
    _Pragma("unroll")                                           \
    for (int off = 32; off >= 1; off >>= 1) {                   \
      mnx = fminf(mnx, __shfl_xor(mnx, off));                   \
      mxx = fmaxf(mxx, __shfl_xor(mxx, off));                   \
      mny = fminf(mny, __shfl_xor(mny, off));                   \
      mxy = fmaxf(mxy, __shfl_xor(mxy, off));                   \
      mnz = fminf(mnz, __shfl_xor(mnz, off));                   \
      mxz = fmaxf(mxz, __shfl_xor(mxz, off));                   \
    }                                                           \
    if (lane == c) {                                            \
      bmnx = mnx; bmxx = mxx; bmny = mny;                       \
      bmxy = mxy; bmnz = mnz; bmxz = mxz;                       \
    }                                                           \
  }
  CH_LIST(INIT_CH)
#undef INIT_CH

#define PIN_CH(c, acc) asm volatile("" : "+v"(z##c));
  CH_LIST(PIN_CH)
#undef PIN_CH

  if (t < 6) slot[t / 2][t & 1] = 0ull;
  if (t == 0) fps_lds[0] = 0;
  __syncthreads();

  float cx = X[0], cy = Y[0], cz = Z[0];
  float gd = __builtin_inff();
  u64 gkey = 0ull;
  float gz = 0.0f;
  int wmaxch = 0;

#define MK(c) ((((u64)__float_as_uint(d##c)) << 32) | (u64)lo##c)
#define KSEL(ka, za, kb, zb, ko, zo)          \
  {                                           \
    const u64 ka_ = (ka), kb_ = (kb);         \
    const bool g_ = ka_ > kb_;                \
    ko = g_ ? ka_ : kb_;                      \
    zo = g_ ? (za) : (zb);                    \
  }

  for (int i = 1; i < NCTR; ++i) {
    const float ux = fmaxf(fmaxf(__fsub_rn(bmnx, cx), __fsub_rn(cx, bmxx)), 0.0f);
    const float uy = fmaxf(fmaxf(__fsub_rn(bmny, cy), __fsub_rn(cy, bmxy)), 0.0f);
    const float uz = fmaxf(fmaxf(__fsub_rn(bmnz, cz), __fsub_rn(cz, bmxz)), 0.0f);
    const float lb = __fadd_rn(__fadd_rn(__fmul_rn(ux, ux), __fmul_rn(uy, uy)),
                               __fmul_rn(uz, uz));
    const u32 mask = (u32)__ballot(!(__fmul_rn(lb, 0.9999f) >= gd));
    if (mask != 0u) {
      if (__builtin_popcount(mask) >= 6) {
#define UPDU_CH(c, acc)                                                  \
        {                                                                \
          const float2 xy =                                              \
              *(const float2*)(sxy + 2 * (((c) << 10) + wbase));         \
          const float dd = sq_dist(xy.x, xy.y, z##c, cx, cy, cz);        \
          d##c = fminf(d##c, dd);                                        \
        }
        CH_LIST(UPDU_CH)
#undef UPDU_CH
      } else {
#define UPDG_CH(c, acc)                                                  \
        if (mask & (1u << (c))) {                                        \
          const float2 xy =                                              \
              *(const float2*)(sxy + 2 * (((c) << 10) + wbase));         \
          float dd = sq_dist(xy.x, xy.y, z##c, cx, cy, cz);              \
          asm volatile("" : "+v"(dd));                                   \
          d##c = fminf(d##c, dd);                                        \
        }
        CH_LIST(UPDG_CH)
#undef UPDG_CH
      }
      if ((mask >> wmaxch) & 1u) {
        u64 m0, m1, m2, m3, m4, m5, m6, m7, q0, q1, q2, q3, h0, h1, kk;
        float n0, n1, n2, n3, n4, n5, n6, n7, r0, r1, r2, r3, e0, e1, bz;
        KSEL(MK(0), z0, MK(1), z1, m0, n0)    KSEL(MK(2), z2, MK(3), z3, m1, n1)
        KSEL(MK(4), z4, MK(5), z5, m2, n2)    KSEL(MK(6), z6, MK(7), z7, m3, n3)
        KSEL(MK(8), z8, MK(9), z9, m4, n4)    KSEL(MK(10), z10, MK(11), z11, m5, n5)
        KSEL(MK(12), z12, MK(13), z13, m6, n6) KSEL(MK(14), z14, MK(15), z15, m7, n7)
        KSEL(m0, n0, m1, n1, q0, r0)  KSEL(m2, n2, m3, n3, q1, r1)
        KSEL(m4, n4, m5, n5, q2, r2)  KSEL(m6, n6, m7, n7, q3, r3)
        KSEL(q0, r0, q1, r1, h0, e0)  KSEL(q2, r2, q3, r3, h1, e1)
        KSEL(h0, e0, h1, e1, kk, bz)
#pragma unroll
        for (int off = 32; off >= 1; off >>= 1) {
          const u64 ok = __shfl_xor(kk, off);
          const float oz = __shfl_xor(bz, off);
          const bool g_ = ok > kk;
          kk = g_ ? ok : kk;
          bz = g_ ? oz : bz;
        }
        gkey = kk;
        gz = bz;
        gd = __uint_as_float((u32)(gkey >> 32));
        wmaxch = (int)(((u32)gkey >> 10) & 15u);
      }
    }
    const int si = i % 3;
    if (lane == 0) {
      s_zw[si][w] = gz;
      atomicMax(&slot[si][w & 1], gkey);
    }
    if (t == 0) {
      const int nsi = si == 2 ? 0 : si + 1;
      slot[nsi][0] = 0ull;
      slot[nsi][1] = 0ull;
    }
    __syncthreads();

    const u64 m = kmax(slot[si][0], slot[si][1]);
    const u32 lowb = (u32)m;
    const int pw = (int)(lowb & 0x3FFFu);
    if (t == 0) fps_lds[i] = 16383 - (int)((lowb >> 14) & 0x3FFFu);

    const int pu = __builtin_amdgcn_readfirstlane(pw);
    const float2 cxy = *(const float2*)(sxy + 2 * pu);
    cx = cxy.x;
    cy = cxy.y;
    cz = s_zw[si][(pu >> 6) & 15];
  }
#undef MK
#undef KSEL

  __syncthreads();
  for (int e = t; e < NCTR; e += 1024) fps_idx[b * NCTR + e] = fps_lds[e];
}

__global__ __launch_bounds__(256) void ballq_kernel(const float* __restrict__ xyz,
                                                    const int* __restrict__ fps_idx,
                                                    int* __restrict__ ball_idx) {
  const int gw = (blockIdx.x * 256 + threadIdx.x) >> 6;
  const int lane = threadIdx.x & 63;
  const int b = gw >> 10;
  const float* X = xyz + (size_t)b * 3 * NPTS;
  const float* Y = X + NPTS;
  const float* Z = X + 2 * NPTS;
  const int c = fps_idx[gw];
  const float cx = X[c], cy = Y[c], cz = Z[c];
  int* out = ball_idx + (size_t)gw * 32;
  const float R2 = 0.04f;

  int cnt = 0, first = -1;
  for (int base = 0; base < NPTS; base += 64) {
    const int j = base + lane;
    const float d = sq_dist(X[j], Y[j], Z[j], cx, cy, cz);
    const bool inb = !(d > R2);
    const unsigned long long m = __ballot(inb);
    if (first < 0 && m != 0ull) first = base + __ffsll(m) - 1;
    if (inb) {
      const int pos = cnt + __popcll(m & ((1ull << lane) - 1ull));
      if (pos < 32) out[pos] = j;
    }
    cnt += __popcll(m);
    if (cnt >= 32) break;
  }
  for (int k = cnt + lane; k < 32; k += 64) out[k] = first;
}

__global__ __launch_bounds__(256, 2) void mlp_kernel_np(
    const float* __restrict__ xyz, const float* __restrict__ points,
    const int* __restrict__ fps_idx, const int* __restrict__ ball_idx,
    const float* __restrict__ wt0, const float* __restrict__ b0,
    const float* __restrict__ wt1, const float* __restrict__ b1,
    const float* __restrict__ wt2, const float* __restrict__ b2,
    float* __restrict__ out) {
  const int bx = blockIdx.x, b = blockIdx.y, t = threadIdx.x;
  const int s = (bx & 7) * 128 + (bx >> 3);

  __shared__ float A1[64 * 36];
  __shared__ float A2[128 * 36];
  __shared__ float S[8704];
  __shared__ float bias_sh[256];
  __shared__ int jidx[32];
  __shared__ float ctr[3];

  const int g = b * NCTR + s;

  if (t < 32) jidx[t] = ball_idx[(size_t)g * 32 + t];
  if (t < 3) ctr[t] = xyz[((size_t)b * 3 + t) * NPTS + fps_idx[g]];
  float* A0 = S;
  float* Wt0 = S + 67 * 36;
  for (int e = t; e < 67 * 64; e += 256) {
    int c = e >> 6, o = e & 63;
    Wt0[c * 68 + o] = wt0[e];
  }
  if (t < 64) bias_sh[t] = b0[t];
  __syncthreads();

  for (int e = t; e < 67 * 32; e += 256) {
    int c = e >> 5, k = e & 31;
    int j = jidx[k];
    float v;
    if (c < 3)
      v = xyz[((size_t)b * 3 + c) * NPTS + j] - ctr[c];
    else
      v = points[((size_t)b * 64 + (c - 3)) * NPTS + j];
    A0[c * 36 + k] = v;
  }
  __syncthreads();

  {
    const int o0 = (t & 31) * 2;
    const int k0 = (t >> 5) * 4;
    float acc[4][2] = {{0.f, 0.f}, {0.f, 0.f}, {0.f, 0.f}, {0.f, 0.f}};
    for (int c = 0; c < 67; ++c) {
      const float4 a = *(const float4*)(A0 + c * 36 + k0);
      const float2 wv = *(const float2*)(Wt0 + c * 68 + o0);
      acc[0][0] = fmaf(a.x, wv.x, acc[0][0]);
      acc[1][0] = fmaf(a.y, wv.x, acc[1][0]);
      acc[2][0] = fmaf(a.z, wv.x, acc[2][0]);
      acc[3][0] = fmaf(a.w, wv.x, acc[3][0]);
      acc[0][1] = fmaf(a.x, wv.y, acc[0][1]);
      acc[1][1] = fmaf(a.y, wv.y, acc[1][1]);
      acc[2][1] = fmaf(a.z, wv.y, acc[2][1]);
      acc[3][1] = fmaf(a.w, wv.y, acc[3][1]);
    }
#pragma unroll
    for (int i = 0; i < 2; ++i) {
      const float bb = bias_sh[o0 + i];
      float4 r;
      r.x = silu_f(acc[0][i] + bb);
      r.y = silu_f(acc[1][i] + bb);
      r.z = silu_f(acc[2][i] + bb);
      r.w = silu_f(acc[3][i] + bb);
      *(float4*)(A1 + (o0 + i) * 36 + k0) = r;
    }
  }
  __syncthreads();

  float* Wt1 = S;
  for (int e = t; e < 128 * 64; e += 256) {
    int c = e >> 7, o = e & 127;
    Wt1[c * 132 + o] = wt1[e];
  }
  if (t < 128) bias_sh[t] = b1[t];
  __syncthreads();

  {
    const int o0 = (t & 31) * 4;
    const int k0 = (t >> 5) * 4;
    float acc[4][4];
#pragma unroll
    for (int kk = 0; kk < 4; ++kk)
#pragma unroll
      for (int oo = 0; oo < 4; ++oo) acc[kk][oo] = 0.f;
    for (int c = 0; c < 64; ++c) {
      const float4 a = *(const float4*)(A1 + c * 36 + k0);
      const float4 w = *(const float4*)(Wt1 + c * 132 + o0);
      const float av[4] = {a.x, a.y, a.z, a.w};
      const float wv[4] = {w.x, w.y, w.z, w.w};
#pragma unroll
      for (int kk = 0; kk < 4; ++kk)
#pragma unroll
        for (int oo = 0; oo < 4; ++oo)
          acc[kk][oo] = fmaf(av[kk], wv[oo], acc[kk][oo]);
    }
#pragma unroll
    for (int oo = 0; oo < 4; ++oo) {
      const float bb = bias_sh[o0 + oo];
      float4 r;
      r.x = silu_f(acc[0][oo] + bb);
      r.y = silu_f(acc[1][oo] + bb);
      r.z = silu_f(acc[2][oo] + bb);
      r.w = silu_f(acc[3][oo] + bb);
      *(float4*)(A2 + (o0 + oo) * 36 + k0) = r;
    }
  }
  __syncthreads();

  float* Wt2 = S;
  float* P = A1;
  const int o0 = (t & 31) * 2;
  const int k0 = (t >> 5) * 4;
  const int kg = t >> 5;
  for (int chunk = 0; chunk < 4; ++chunk) {
    for (int e = t; e < 64 * 128; e += 256) {
      int c = e >> 6, o = e & 63;
      Wt2[c * 68 + o] = wt2[c * 256 + chunk * 64 + o];
    }
    if (t < 64) bias_sh[t] = b2[chunk * 64 + t];
    __syncthreads();

    float acc[4][2] = {{0.f, 0.f}, {0.f, 0.f}, {0.f, 0.f}, {0.f, 0.f}};
    for (int c = 0; c < 128; ++c) {
      const float4 a = *(const float4*)(A2 + c * 36 + k0);
      const float2 wv = *(const float2*)(Wt2 + c * 68 + o0);
      acc[0][0] = fmaf(a.x, wv.x, acc[0][0]);
      acc[1][0] = fmaf(a.y, wv.x, acc[1][0]);
      acc[2][0] = fmaf(a.z, wv.x, acc[2][0]);
      acc[3][0] = fmaf(a.w, wv.x, acc[3][0]);
      acc[0][1] = fmaf(a.x, wv.y, acc[0][1]);
      acc[1][1] = fmaf(a.y, wv.y, acc[1][1]);
      acc[2][1] = fmaf(a.z, wv.y, acc[2][1]);
      acc[3][1] = fmaf(a.w, wv.y, acc[3][1]);
    }
#pragma unroll
    for (int i = 0; i < 2; ++i) {
      const float bb = bias_sh[o0 + i];
      float sum = silu_f(acc[0][i] + bb) + silu_f(acc[1][i] + bb) +
                  silu_f(acc[2][i] + bb) + silu_f(acc[3][i] + bb);
      P[(o0 + i) * 9 + kg] = sum;
    }
    __syncthreads();
    if (t < 64) {
      float tot = 0.f;
#pragma unroll
      for (int q = 0; q < 8; ++q) tot += P[t * 9 + q];
      out[((size_t)b * 256 + chunk * 64 + t) * NCTR + s] = tot * (1.0f / 32.0f);
    }
    __syncthreads();
  }
}

extern "C" void kernel_launch(void* const* d_in, const int* in_sizes, int n_in,
                              void* d_out, int out_size, void* d_ws, size_t ws_size,
                              hipStream_t stream) {
  const float* xyz = (const float*)d_in[0];
  const float* points = (const float*)d_in[1];
  const float* w0 = (const float*)d_in[2];
  const float* b0 = (const float*)d_in[3];
  const float* w1 = (const float*)d_in[4];
  const float* b1 = (const float*)d_in[5];
  const float* w2 = (const float*)d_in[6];
  const float* b2 = (const float*)d_in[7];
  float* out = (float*)d_out;

  int* fps = (int*)d_ws;                       // 8K ints
  int* bidx = (int*)d_ws + 8192;               // 256K ints (fallback only)
  u32* progress = (u32*)bidx;                  // first 8 u32 (coop path only)
  float* wt0 = (float*)d_ws + 270336;          // 67*64
  float* wt1 = wt0 + 67 * 64;                  // 64*128
  float* wt2 = wt1 + 64 * 128;                 // 128*256
  float* sxg = (float*)d_ws + 315584;          // 8*16384 sorted x
  float* syg = sxg + BATCH * NPTS;             // sorted y
  float* szg = syg + BATCH * NPTS;             // sorted z
  int* sog = (int*)(szg + BATCH * NPTS);       // sorted orig idx
  float* points_t = (float*)d_ws + 839872;     // [B][N][64] = 32 MB
  const size_t ws_need = ((size_t)839872 + (size_t)BATCH * NPTS * 64) * 4;

  transpose_w_kernel<<<64, 256, 0, stream>>>(w0, w1, w2, wt0, wt1, wt2, progress);
  sort_kernel<<<BATCH, 1024, 0, stream>>>(xyz, sxg, syg, szg, sog);

  const bool use_pt = ws_size >= ws_need;
  if (use_pt) {
    transpose_p_kernel<<<dim3(NPTS / 64, BATCH), 256, 0, stream>>>(points,
                                                                   points_t);
    void* args[] = {(void*)&xyz, (void*)&points_t, (void*)&sxg, (void*)&syg,
                    (void*)&szg, (void*)&sog, (void*)&fps, (void*)&progress,
                    (void*)&wt0, (void*)&b0, (void*)&wt1, (void*)&b1,
                    (void*)&wt2, (void*)&b2, (void*)&out};
    hipError_t err = hipLaunchCooperativeKernel(
        reinterpret_cast<const void*>(mega_kernel), dim3(GRID_MEGA), dim3(1024),
        args, 0, stream);
    if (err == hipSuccess) return;
  }
  // fallback: measured serial pipeline
  fps_kernel<<<BATCH, 1024, 0, stream>>>(xyz, sxg, syg, szg, sog, fps);
  ballq_kernel<<<2048, 256, 0, stream>>>(xyz, fps, bidx);
  mlp_kernel_np<<<dim3(NCTR, BATCH), 256, 0, stream>>>(xyz, points, fps, bidx,
                                                       wt0, b0, wt1, b1, wt2,
                                                       b2, out);
}

// Round 16
// 1763.394 us; speedup vs baseline: 2.1484x; 2.1484x over previous
//
#include <hip/hip_runtime.h>
#include <math.h>

#define NPTS 16384
#define NCTR 1024
#define BATCH 8
#define NCELL 512   // 8x8x8 Morton cells
#define NCONS 240   // consumer blocks in the mega kernel
#define GRID_MEGA (BATCH + NCONS)

typedef unsigned long long u64;
typedef unsigned int u32;

// Bit-exact squared distance matching numpy: ((dx*dx + dy*dy) + dz*dz),
// each op individually IEEE-rounded (no FMA contraction).
__device__ __forceinline__ float sq_dist(float x, float y, float z,
                                         float cx, float cy, float cz) {
  float dx = __fsub_rn(x, cx);
  float dy = __fsub_rn(y, cy);
  float dz = __fsub_rn(z, cz);
  return __fadd_rn(__fadd_rn(__fmul_rn(dx, dx), __fmul_rn(dy, dy)), __fmul_rn(dz, dz));
}

__device__ __forceinline__ float silu_f(float x) {
  return x / (1.0f + __expf(-x));
}

__device__ __forceinline__ u64 kmax(u64 a, u64 b) { return a > b ? a : b; }

__device__ __forceinline__ int morton_cell(float x, float y, float z) {
  int mx = min(7, max(0, (int)(x * 8.0f)));
  int my = min(7, max(0, (int)(y * 8.0f)));
  int mz = min(7, max(0, (int)(z * 8.0f)));
  int m = 0;
#pragma unroll
  for (int k = 0; k < 3; ++k) {
    m |= ((mx >> k) & 1) << (3 * k + 2);
    m |= ((my >> k) & 1) << (3 * k + 1);
    m |= ((mz >> k) & 1) << (3 * k + 0);
  }
  return m;
}

// ---------------------------------------------------------------------------
// Kernel 0: DETERMINISTIC Morton counting sort, one block per batch.
// ---------------------------------------------------------------------------
__global__ __launch_bounds__(1024) void sort_kernel(
    const float* __restrict__ xyz, float* __restrict__ sxg,
    float* __restrict__ syg, float* __restrict__ szg, int* __restrict__ sog) {
  const int b = blockIdx.x, t = threadIdx.x;
  const float* X = xyz + (size_t)b * 3 * NPTS;
  const float* Y = X + NPTS;
  const float* Z = X + 2 * NPTS;
  __shared__ int cnt[NCELL];
  __shared__ int off[NCELL];
  __shared__ int start[NCELL];
  __shared__ int so_l[NPTS];  // 64 KB
  for (int e = t; e < NCELL; e += 1024) cnt[e] = 0;
  __syncthreads();
#pragma unroll
  for (int j = 0; j < 16; ++j) {
    const int n = t + (j << 10);
    atomicAdd(&cnt[morton_cell(X[n], Y[n], Z[n])], 1);
  }
  __syncthreads();
  if (t < NCELL) off[t] = cnt[t];
  __syncthreads();
  for (int d = 1; d < NCELL; d <<= 1) {  // Hillis-Steele inclusive scan
    int v = 0;
    if (t < NCELL) { v = off[t]; if (t >= d) v += off[t - d]; }
    __syncthreads();
    if (t < NCELL) off[t] = v;
    __syncthreads();
  }
  if (t < NCELL) { off[t] -= cnt[t]; start[t] = off[t]; }
  __syncthreads();
  // phase A: ORDERED scatter in 16 rounds -> nearly-sorted cell contents
  for (int j = 0; j < 16; ++j) {
    const int n = t + (j << 10);
    const int pos = atomicAdd(&off[morton_cell(X[n], Y[n], Z[n])], 1);
    so_l[pos] = n;
    __syncthreads();
  }
  // phase B: deterministic intra-cell order (ascending orig index)
  if (t < NCELL) {
    const int s0 = start[t], k = cnt[t];
    for (int i2 = 1; i2 < k; ++i2) {
      const int key = so_l[s0 + i2];
      int j2 = i2 - 1;
      while (j2 >= 0 && so_l[s0 + j2] > key) {
        so_l[s0 + j2 + 1] = so_l[s0 + j2];
        --j2;
      }
      so_l[s0 + j2 + 1] = key;
    }
  }
  __syncthreads();
  // phase C: deterministic rebuild
  float* sx = sxg + (size_t)b * NPTS;
  float* sy = syg + (size_t)b * NPTS;
  float* sz = szg + (size_t)b * NPTS;
  int* so = sog + (size_t)b * NPTS;
#pragma unroll
  for (int j = 0; j < 16; ++j) {
    const int pos = t + (j << 10);
    const int n = so_l[pos];
    so[pos] = n;
    sx[pos] = X[n];
    sy[pos] = Y[n];
    sz[pos] = Z[n];
  }
}

// ---------------------------------------------------------------------------
// Kernel 2b: weight transpose + progress zeroing (runs before mega kernel).
// ---------------------------------------------------------------------------
__global__ __launch_bounds__(256) void transpose_w_kernel(
    const float* __restrict__ w0, const float* __restrict__ w1,
    const float* __restrict__ w2, float* __restrict__ wt0,
    float* __restrict__ wt1, float* __restrict__ wt2,
    u32* __restrict__ progress) {
  const int t0 = blockIdx.x * 256 + threadIdx.x;
  if (t0 < BATCH) progress[t0] = 0u;  // re-zero each graph replay
  const int stride = gridDim.x * 256;
  for (int e = t0; e < 64 * 67; e += stride) {
    int o = e / 67, c = e - o * 67;
    wt0[c * 64 + o] = w0[e];
  }
  for (int e = t0; e < 128 * 64; e += stride) {
    int o = e >> 6, c = e & 63;
    wt1[c * 128 + o] = w1[e];
  }
  for (int e = t0; e < 256 * 128; e += stride) {
    int o = e >> 7, c = e & 127;
    wt2[c * 256 + o] = w2[e];
  }
}

// ---------------------------------------------------------------------------
// Kernel 2c: points transpose [B][64][N] -> [B][N][64] (coalesced gather).
// ---------------------------------------------------------------------------
__global__ __launch_bounds__(256) void transpose_p_kernel(
    const float* __restrict__ points, float* __restrict__ points_t) {
  __shared__ float tile[64 * 65];
  const int b = blockIdx.y;
  const int n0 = blockIdx.x * 64;
  const int t = threadIdx.x;
  const float* src = points + (size_t)b * 64 * NPTS;
  float* dst = points_t + (size_t)b * NPTS * 64;
#pragma unroll
  for (int i = 0; i < 16; ++i) {
    const int e = t + (i << 8);
    const int c = e >> 6, ni = e & 63;
    tile[c * 65 + ni] = src[(size_t)c * NPTS + n0 + ni];  // coalesced read
  }
  __syncthreads();
#pragma unroll
  for (int i = 0; i < 16; ++i) {
    const int f = t + (i << 8);
    const int n = f >> 6, c = f & 63;
    dst[(size_t)(n0 + n) * 64 + c] = tile[c * 65 + n];    // coalesced write
  }
}

// ---------------------------------------------------------------------------
// MEGA KERNEL v3. R15 PMC decomposition: FETCH 1.537GB = 188KB/item == the
// weight set (wt2 128K + wt1 32K + wt0 17K) — consumer L2s evict the weights
// between items under the scan/gather streams. WRITE 157MB for an 8MB output
// == 16x partial-line writeback (neighboring-s items on different XCDs).
// Fixes, keeping the twice-validated producer/consumer skeleton:
//  (1) wt2 staged ONCE per consumer block into LDS (131072B); activations
//      alias: A0 = head of R, A2 = R (A0 dead before A2 written), P = A1
//      (A1 dead before P written). Consumer LDS ~155KB >= producer 135.7KB.
//  (2) items grouped 16-consecutive-s per block: all 16 writers of each
//      64B output line run in one block/XCD -> full-line writeback.
// wt0/wt1 stay global (49KB; L2-hot once wt2's 128KB/item stream is gone).
// ---------------------------------------------------------------------------
#define CH_LIST(F) \
  F(0,a0)  F(1,a1)  F(2,a2)  F(3,a3)  F(4,a0)  F(5,a1)  F(6,a2)  F(7,a3)  \
  F(8,a0)  F(9,a1)  F(10,a2) F(11,a3) F(12,a0) F(13,a1) F(14,a2) F(15,a3)

union __align__(16) MegaSmem {
  struct {
    float sxy[2 * NPTS];   // 128 KB interleaved sorted x,y
    u64 slot[3][2];
    float s_zw[3][16];
    int fps_lds[NCTR];
  } p;
  struct {
    float wt2l[128 * 256]; // 128 KB: layer-2 weights, staged once per block
    float R[128 * 36];     // A2 [128][36]; A0 [67][36] aliases its head
    float A1[64 * 36];     // layer0 out; P[256*9] aliases
    int jidx[32];
    float ctr[3];
  } c;
};

__global__ __launch_bounds__(1024)
void mega_kernel(const float* __restrict__ xyz, const float* __restrict__ points_t,
                 const float* __restrict__ sxg, const float* __restrict__ syg,
                 const float* __restrict__ szg, const int* __restrict__ sog,
                 int* __restrict__ fps_g, u32* __restrict__ progress,
                 const float* __restrict__ wt0, const float* __restrict__ b0,
                 const float* __restrict__ wt1, const float* __restrict__ b1,
                 const float* __restrict__ wt2, const float* __restrict__ b2,
                 float* __restrict__ out) {
  __shared__ MegaSmem sm;
  const int t = threadIdx.x;

  if (blockIdx.x < BATCH) {
    // ============================ PRODUCER (fps) ============================
    const int b = blockIdx.x;
    const int w = t >> 6, lane = t & 63;
    const float* X = xyz + (size_t)b * 3 * NPTS;
    const float* Y = X + NPTS;
    const float* Z = X + 2 * NPTS;
    const float* SX = sxg + (size_t)b * NPTS;
    const float* SY = syg + (size_t)b * NPTS;
    const float* SZ = szg + (size_t)b * NPTS;
    const int* SO = sog + (size_t)b * NPTS;

#define DECL_CH(c, acc) float z##c, d##c; u32 lo##c;
    CH_LIST(DECL_CH)
#undef DECL_CH

    const int wbase = (w << 6) + lane;  // INTERLEAVED mapping base

    float bmnx = __builtin_inff(), bmxx = -__builtin_inff();
    float bmny = __builtin_inff(), bmxy = -__builtin_inff();
    float bmnz = __builtin_inff(), bmxz = -__builtin_inff();

#define INIT_CH(c, acc)                                         \
    {                                                           \
      const int p = ((c) << 10) + wbase;                        \
      const float xv = SX[p], yv = SY[p], zv = SZ[p];           \
      sm.p.sxy[2 * p] = xv; sm.p.sxy[2 * p + 1] = yv;           \
      z##c = zv;                                                \
      const int o = SO[p];                                      \
      lo##c = ((u32)(16383 - o) << 14) | (u32)p;                \
      d##c = __builtin_inff();                                  \
      float mnx = xv, mxx = xv, mny = yv, mxy = yv;             \
      float mnz = zv, mxz = zv;                                 \
      _Pragma("unroll")                                         \
      for (int off = 32; off >= 1; off >>= 1) {                 \
        mnx = fminf(mnx, __shfl_xor(mnx, off));                 \
        mxx = fmaxf(mxx, __shfl_xor(mxx, off));                 \
        mny = fminf(mny, __shfl_xor(mny, off));                 \
        mxy = fmaxf(mxy, __shfl_xor(mxy, off));                 \
        mnz = fminf(mnz, __shfl_xor(mnz, off));                 \
        mxz = fmaxf(mxz, __shfl_xor(mxz, off));                 \
      }                                                         \
      if (lane == c) {                                          \
        bmnx = mnx; bmxx = mxx; bmny = mny;                     \
        bmxy = mxy; bmnz = mnz; bmxz = mxz;                     \
      }                                                         \
    }
    CH_LIST(INIT_CH)
#undef INIT_CH

#define PIN_CH(c, acc) asm volatile("" : "+v"(z##c));
    CH_LIST(PIN_CH)
#undef PIN_CH

    if (t < 6) sm.p.slot[t / 2][t & 1] = 0ull;
    if (t == 0) sm.p.fps_lds[0] = 0;
    __syncthreads();  // LDS staging complete, slots zeroed

    float cx = X[0], cy = Y[0], cz = Z[0];
    float gd = __builtin_inff();
    u64 gkey = 0ull;
    float gz = 0.0f;
    int wmaxch = 0;

#define MK(c) ((((u64)__float_as_uint(d##c)) << 32) | (u64)lo##c)
#define KSEL(ka, za, kb, zb, ko, zo)          \
    {                                         \
      const u64 ka_ = (ka), kb_ = (kb);       \
      const bool g_ = ka_ > kb_;              \
      ko = g_ ? ka_ : kb_;                    \
      zo = g_ ? (za) : (zb);                  \
    }

    for (int i = 1; i < NCTR; ++i) {
      const float ux = fmaxf(fmaxf(__fsub_rn(bmnx, cx), __fsub_rn(cx, bmxx)), 0.0f);
      const float uy = fmaxf(fmaxf(__fsub_rn(bmny, cy), __fsub_rn(cy, bmxy)), 0.0f);
      const float uz = fmaxf(fmaxf(__fsub_rn(bmnz, cz), __fsub_rn(cz, bmxz)), 0.0f);
      const float lb = __fadd_rn(__fadd_rn(__fmul_rn(ux, ux), __fmul_rn(uy, uy)),
                                 __fmul_rn(uz, uz));
      const u32 mask = (u32)__ballot(!(__fmul_rn(lb, 0.9999f) >= gd));
      if (mask != 0u) {
        if (__builtin_popcount(mask) >= 6) {
#define UPDU_CH(c, acc)                                                    \
          {                                                                \
            const float2 xy =                                              \
                *(const float2*)(sm.p.sxy + 2 * (((c) << 10) + wbase));    \
            const float dd = sq_dist(xy.x, xy.y, z##c, cx, cy, cz);        \
            d##c = fminf(d##c, dd);                                        \
          }
          CH_LIST(UPDU_CH)
#undef UPDU_CH
        } else {
#define UPDG_CH(c, acc)                                                    \
          if (mask & (1u << (c))) {                                        \
            const float2 xy =                                              \
                *(const float2*)(sm.p.sxy + 2 * (((c) << 10) + wbase));    \
            float dd = sq_dist(xy.x, xy.y, z##c, cx, cy, cz);              \
            asm volatile("" : "+v"(dd));                                   \
            d##c = fminf(d##c, dd);                                        \
          }
          CH_LIST(UPDG_CH)
#undef UPDG_CH
        }
        if ((mask >> wmaxch) & 1u) {
          u64 m0, m1, m2, m3, m4, m5, m6, m7, q0, q1, q2, q3, h0, h1, kk;
          float n0, n1, n2, n3, n4, n5, n6, n7, r0, r1, r2, r3, e0, e1, bz;
          KSEL(MK(0), z0, MK(1), z1, m0, n0)    KSEL(MK(2), z2, MK(3), z3, m1, n1)
          KSEL(MK(4), z4, MK(5), z5, m2, n2)    KSEL(MK(6), z6, MK(7), z7, m3, n3)
          KSEL(MK(8), z8, MK(9), z9, m4, n4)    KSEL(MK(10), z10, MK(11), z11, m5, n5)
          KSEL(MK(12), z12, MK(13), z13, m6, n6) KSEL(MK(14), z14, MK(15), z15, m7, n7)
          KSEL(m0, n0, m1, n1, q0, r0)  KSEL(m2, n2, m3, n3, q1, r1)
          KSEL(m4, n4, m5, n5, q2, r2)  KSEL(m6, n6, m7, n7, q3, r3)
          KSEL(q0, r0, q1, r1, h0, e0)  KSEL(q2, r2, q3, r3, h1, e1)
          KSEL(h0, e0, h1, e1, kk, bz)
#pragma unroll
          for (int off = 32; off >= 1; off >>= 1) {
            const u64 ok = __shfl_xor(kk, off);
            const float oz = __shfl_xor(bz, off);
            const bool g_ = ok > kk;
            kk = g_ ? ok : kk;
            bz = g_ ? oz : bz;
          }
          gkey = kk;
          gz = bz;
          gd = __uint_as_float((u32)(gkey >> 32));
          wmaxch = (int)(((u32)gkey >> 10) & 15u);
        }
      }
      const int si = i % 3;
      if (lane == 0) {
        sm.p.s_zw[si][w] = gz;
        atomicMax(&sm.p.slot[si][w & 1], gkey);
      }
      if (t == 0) {
        const int nsi = si == 2 ? 0 : si + 1;
        sm.p.slot[nsi][0] = 0ull;
        sm.p.slot[nsi][1] = 0ull;
      }
      __syncthreads();  // the ONLY barrier per step

      const u64 m = kmax(sm.p.slot[si][0], sm.p.slot[si][1]);
      const u32 lowb = (u32)m;
      const int pw = (int)(lowb & 0x3FFFu);
      if (t == 0) sm.p.fps_lds[i] = 16383 - (int)((lowb >> 14) & 0x3FFFu);

      const int pu = __builtin_amdgcn_readfirstlane(pw);
      const float2 cxy = *(const float2*)(sm.p.sxy + 2 * pu);
      cx = cxy.x;
      cy = cxy.y;
      cz = sm.p.s_zw[si][(pu >> 6) & 15];

      // publish a 64-centroid chunk (wave 0; RELEASE orders stores first)
      if (w == 0 && (i & 63) == 63) {
        const int base0 = i - 63;
        fps_g[b * NCTR + base0 + lane] = sm.p.fps_lds[base0 + lane];
        if (lane == 0)
          __hip_atomic_store(&progress[b], (u32)(i + 1), __ATOMIC_RELEASE,
                             __HIP_MEMORY_SCOPE_AGENT);
      }
    }
#undef MK
#undef KSEL
    return;
  }

  // ============================ CONSUMER (ballq+mlp) ========================
  // stage layer-2 weights ONCE per block (32 floats/thread, coalesced)
  for (int e = t; e < 128 * 256; e += 1024) sm.c.wt2l[e] = wt2[e];
  __syncthreads();

  float* A0 = sm.c.R;   // [67][36] aliases head of R
  float* A2 = sm.c.R;   // [128][36]
  float* A1 = sm.c.A1;  // [64][36]
  float* P  = sm.c.A1;  // [256][9] overlays A1 (A1 dead when written)

  const int cb = blockIdx.x - BATCH;  // 0..NCONS-1
  // 512 groups of 16 consecutive s (same batch): full-line output writeback
  for (int grp = cb; grp < BATCH * NCTR / 16; grp += NCONS) {
    const int b_ = grp & 7;
    const int s0 = (grp >> 3) << 4;  // s-chunk-major: early chunks ready first
    if (t == 0) {
      while (__hip_atomic_load(&progress[b_], __ATOMIC_ACQUIRE,
                               __HIP_MEMORY_SCOPE_AGENT) < (u32)(s0 + 16))
        __builtin_amdgcn_s_sleep(64);
    }
    __syncthreads();

    const float* X = xyz + (size_t)b_ * 3 * NPTS;
    const float* Y = X + NPTS;
    const float* Z = X + 2 * NPTS;

    for (int sIt = 0; sIt < 16; ++sIt) {
      const int s = s0 + sIt;

      // ball query by wave 0 -> LDS jidx + ctr
      if (t < 64) {
        const int lane = t;
        const int c = fps_g[b_ * NCTR + s];
        const float cx = X[c], cy = Y[c], cz = Z[c];
        if (lane == 0) { sm.c.ctr[0] = cx; sm.c.ctr[1] = cy; sm.c.ctr[2] = cz; }
        const float R2 = 0.04f;
        int cnt = 0, first = -1;
        for (int base = 0; base < NPTS; base += 64) {
          const int jj = base + lane;
          const float d = sq_dist(X[jj], Y[jj], Z[jj], cx, cy, cz);
          const bool inb = !(d > R2);
          const unsigned long long mm = __ballot(inb);
          if (first < 0 && mm != 0ull) first = base + __ffsll(mm) - 1;
          if (inb) {
            const int pos = cnt + __popcll(mm & ((1ull << lane) - 1ull));
            if (pos < 32) sm.c.jidx[pos] = jj;
          }
          cnt += __popcll(mm);
          if (cnt >= 32) break;
        }
        for (int k2 = cnt + lane; k2 < 32; k2 += 64) sm.c.jidx[k2] = first;
      }
      __syncthreads();

      // gather A0: xyz rows + COALESCED points_t rows (256B/sample segment)
      if (t < 96) {
        const int c = t >> 5, k = t & 31;
        A0[c * 36 + k] =
            xyz[((size_t)b_ * 3 + c) * NPTS + sm.c.jidx[k]] - sm.c.ctr[c];
      }
#pragma unroll
      for (int pass = 0; pass < 2; ++pass) {
        const int e = t + (pass << 10);
        const int c = e & 63, k = e >> 6;
        A0[(c + 3) * 36 + k] =
            points_t[((size_t)b_ * NPTS + sm.c.jidx[k]) * 64 + c];
      }
      __syncthreads();

      // layer 0 (67 -> 64): 512 threads, o = t&63, kg = t>>6
      if (t < 512) {
        const int o = t & 63, k0 = (t >> 6) * 4;
        const float bb = b0[o];
        float a0 = 0.f, a1 = 0.f, a2 = 0.f, a3 = 0.f;
        for (int c = 0; c < 67; ++c) {
          const float4 a = *(const float4*)(A0 + c * 36 + k0);
          const float wv = wt0[c * 64 + o];  // global (L2-hot, 17KB)
          a0 = fmaf(a.x, wv, a0);
          a1 = fmaf(a.y, wv, a1);
          a2 = fmaf(a.z, wv, a2);
          a3 = fmaf(a.w, wv, a3);
        }
        float4 r;
        r.x = silu_f(a0 + bb);
        r.y = silu_f(a1 + bb);
        r.z = silu_f(a2 + bb);
        r.w = silu_f(a3 + bb);
        *(float4*)(A1 + o * 36 + k0) = r;
      }
      __syncthreads();

      // layer 1 (64 -> 128): 1024 threads; writes A2 (=R, A0 now dead)
      {
        const int o = t & 127, k0 = (t >> 7) * 4;
        const float bb = b1[o];
        float a0 = 0.f, a1 = 0.f, a2 = 0.f, a3 = 0.f;
        for (int c = 0; c < 64; ++c) {
          const float4 a = *(const float4*)(A1 + c * 36 + k0);
          const float wv = wt1[c * 128 + o];  // global (L2-hot, 32KB)
          a0 = fmaf(a.x, wv, a0);
          a1 = fmaf(a.y, wv, a1);
          a2 = fmaf(a.z, wv, a2);
          a3 = fmaf(a.w, wv, a3);
        }
        float4 r;
        r.x = silu_f(a0 + bb);
        r.y = silu_f(a1 + bb);
        r.z = silu_f(a2 + bb);
        r.w = silu_f(a3 + bb);
        *(float4*)(A2 + o * 36 + k0) = r;
      }
      __syncthreads();

      // layer 2 (128 -> 256): weights from LDS; P overlays A1 (dead)
      {
        const int o = t & 127, kg = t >> 7, k0 = kg * 4;
#pragma unroll
        for (int half = 0; half < 2; ++half) {
          const int oo = half * 128 + o;
          const float bb = b2[oo];
          float a0 = 0.f, a1 = 0.f, a2 = 0.f, a3 = 0.f;
          for (int c = 0; c < 128; ++c) {
            const float4 a = *(const float4*)(A2 + c * 36 + k0);
            const float wv = sm.c.wt2l[c * 256 + oo];  // LDS, conflict-free
            a0 = fmaf(a.x, wv, a0);
            a1 = fmaf(a.y, wv, a1);
            a2 = fmaf(a.z, wv, a2);
            a3 = fmaf(a.w, wv, a3);
          }
          const float sum = silu_f(a0 + bb) + silu_f(a1 + bb) +
                            silu_f(a2 + bb) + silu_f(a3 + bb);
          P[oo * 9 + kg] = sum;
        }
      }
      __syncthreads();

      // mean over the 8 k-groups (same q-order as serial) + output
      if (t < 256) {
        float tot = 0.f;
#pragma unroll
        for (int q = 0; q < 8; ++q) tot += P[t * 9 + q];
        out[((size_t)b_ * 256 + t) * NCTR + s] = tot * (1.0f / 32.0f);
      }
      __syncthreads();  // LDS reuse safe for next item
    }
  }
}

// ---------------------------------------------------------------------------
// FALLBACK PATH (if cooperative launch rejected): serial pipeline.
// ---------------------------------------------------------------------------
__global__ __launch_bounds__(1024)
void fps_kernel(const float* __restrict__ xyz, const float* __restrict__ sxg,
                const float* __restrict__ syg, const float* __restrict__ szg,
                const int* __restrict__ sog, int* __restrict__ fps_idx) {
  const int b = blockIdx.x;
  const int t = threadIdx.x;
  const int w = t >> 6, lane = t & 63;
  const float* X = xyz + (size_t)b * 3 * NPTS;
  const float* Y = X + NPTS;
  const float* Z = X + 2 * NPTS;
  const float* SX = sxg + (size_t)b * NPTS;
  const float* SY = syg + (size_t)b * NPTS;
  const float* SZ = szg + (size_t)b * NPTS;
  const int* SO = sog + (size_t)b * NPTS;

  __shared__ float sxy[2 * NPTS];
  __shared__ __align__(16) u64 slot[3][2];
  __shared__ float s_zw[3][16];
  __shared__ int fps_lds[NCTR];

#define DECL_CH(c, acc) float z##c, d##c; u32 lo##c;
  CH_LIST(DECL_CH)
#undef DECL_CH

  const int wbase = (w << 6) + lane;

  float bmnx = __builtin_inff(), bmxx = -__builtin_inff();
  float bmny = __builtin_inff(), bmxy = -__builtin_inff();
  float bmnz = __builtin_inff(), bmxz = -__builtin_inff();

#define INIT_CH(c, acc)                                         \
  {                                                             \
    const int p = ((c) << 10) + wbase;                          \
    const float xv = SX[p], yv = SY[p], zv = SZ[p];             \
    sxy[2 * p] = xv; sxy[2 * p + 1] = yv;                       \
    z##c = zv;                                                  \
    const int o = SO[p];                                        \
    lo##c = ((u32)(16383 - o) << 14) | (u32)p;                  \
    d##c = __builtin_inff();                                    \
    float mnx = xv, mxx = xv, mny = yv, mxy = yv;               \
    float mnz = zv, mxz = zv;                                   \
    _Pragma("unroll")                                           \
    for (int off = 32; off >= 1; off >>= 1) {                   \
      mnx = fminf(mnx, __shfl_xor(mnx, off));                   \
      mxx = fmaxf(mxx, __shfl_xor(mxx, off));                   \
      mny = fminf(mny, __shfl_xor(mny, off));                   \
      mxy = fmaxf(mxy, __shfl_xor(mxy, off));                   \
      mnz = fminf(mnz, __shfl_xor(mnz, off));                   \
      mxz = fmaxf(mxz, __shfl_xor(mxz, off));                   \
    }                                                           \
    if (lane == c) {                                            \
      bmnx = mnx; bmxx = mxx; bmny = mny;                       \
      bmxy = mxy; bmnz = mnz; bmxz = mxz;                       \
    }                                                           \
  }
  CH_LIST(INIT_CH)
#undef INIT_CH

#define PIN_CH(c, acc) asm volatile("" : "+v"(z##c));
  CH_LIST(PIN_CH)
#undef PIN_CH

  if (t < 6) slot[t / 2][t & 1] = 0ull;
  if (t == 0) fps_lds[0] = 0;
  __syncthreads();

  float cx = X[0], cy = Y[0], cz = Z[0];
  float gd = __builtin_inff();
  u64 gkey = 0ull;
  float gz = 0.0f;
  int wmaxch = 0;

#define MK(c) ((((u64)__float_as_uint(d##c)) << 32) | (u64)lo##c)
#define KSEL(ka, za, kb, zb, ko, zo)          \
  {                                           \
    const u64 ka_ = (ka), kb_ = (kb);         \
    const bool g_ = ka_ > kb_;                \
    ko = g_ ? ka_ : kb_;                      \
    zo = g_ ? (za) : (zb);                    \
  }

  for (int i = 1; i < NCTR; ++i) {
    const float ux = fmaxf(fmaxf(__fsub_rn(bmnx, cx), __fsub_rn(cx, bmxx)), 0.0f);
    const float uy = fmaxf(fmaxf(__fsub_rn(bmny, cy), __fsub_rn(cy, bmxy)), 0.0f);
    const float uz = fmaxf(fmaxf(__fsub_rn(bmnz, cz), __fsub_rn(cz, bmxz)), 0.0f);
    const float lb = __fadd_rn(__fadd_rn(__fmul_rn(ux, ux), __fmul_rn(uy, uy)),
                               __fmul_rn(uz, uz));
    const u32 mask = (u32)__ballot(!(__fmul_rn(lb, 0.9999f) >= gd));
    if (mask != 0u) {
      if (__builtin_popcount(mask) >= 6) {
#define UPDU_CH(c, acc)                                                  \
        {                                                                \
          const float2 xy =                                              \
              *(const float2*)(sxy + 2 * (((c) << 10) + wbase));         \
          const float dd = sq_dist(xy.x, xy.y, z##c, cx, cy, cz);        \
          d##c = fminf(d##c, dd);                                        \
        }
        CH_LIST(UPDU_CH)
#undef UPDU_CH
      } else {
#define UPDG_CH(c, acc)                                                  \
        if (mask & (1u << (c))) {                                        \
          const float2 xy =                                              \
              *(const float2*)(sxy + 2 * (((c) << 10) + wbase));         \
          float dd = sq_dist(xy.x, xy.y, z##c, cx, cy, cz);              \
          asm volatile("" : "+v"(dd));                                   \
          d##c = fminf(d##c, dd);                                        \
        }
        CH_LIST(UPDG_CH)
#undef UPDG_CH
      }
      if ((mask >> wmaxch) & 1u) {
        u64 m0, m1, m2, m3, m4, m5, m6, m7, q0, q1, q2, q3, h0, h1, kk;
        float n0, n1, n2, n3, n4, n5, n6, n7, r0, r1, r2, r3, e0, e1, bz;
        KSEL(MK(0), z0, MK(1), z1, m0, n0)    KSEL(MK(2), z2, MK(3), z3, m1, n1)
        KSEL(MK(4), z4, MK(5), z5, m2, n2)    KSEL(MK(6), z6, MK(7), z7, m3, n3)
        KSEL(MK(8), z8, MK(9), z9, m4, n4)    KSEL(MK(10), z10, MK(11), z11, m5, n5)
        KSEL(MK(12), z12, MK(13), z13, m6, n6) KSEL(MK(14), z14, MK(15), z15, m7, n7)
        KSEL(m0, n0, m1, n1, q0, r0)  KSEL(m2, n2, m3, n3, q1, r1)
        KSEL(m4, n4, m5, n5, q2, r2)  KSEL(m6, n6, m7, n7, q3, r3)
        KSEL(q0, r0, q1, r1, h0, e0)  KSEL(q2, r2, q3, r3, h1, e1)
        KSEL(h0, e0, h1, e1, kk, bz)
#pragma unroll
        for (int off = 32; off >= 1; off >>= 1) {
          const u64 ok = __shfl_xor(kk, off);
          const float oz = __shfl_xor(bz, off);
          const bool g_ = ok > kk;
          kk = g_ ? ok : kk;
          bz = g_ ? oz : bz;
        }
        gkey = kk;
        gz = bz;
        gd = __uint_as_float((u32)(gkey >> 32));
        wmaxch = (int)(((u32)gkey >> 10) & 15u);
      }
    }
    const int si = i % 3;
    if (lane == 0) {
      s_zw[si][w] = gz;
      atomicMax(&slot[si][w & 1], gkey);
    }
    if (t == 0) {
      const int nsi = si == 2 ? 0 : si + 1;
      slot[nsi][0] = 0ull;
      slot[nsi][1] = 0ull;
    }
    __syncthreads();

    const u64 m = kmax(slot[si][0], slot[si][1]);
    const u32 lowb = (u32)m;
    const int pw = (int)(lowb & 0x3FFFu);
    if (t == 0) fps_lds[i] = 16383 - (int)((lowb >> 14) & 0x3FFFu);

    const int pu = __builtin_amdgcn_readfirstlane(pw);
    const float2 cxy = *(const float2*)(sxy + 2 * pu);
    cx = cxy.x;
    cy = cxy.y;
    cz = s_zw[si][(pu >> 6) & 15];
  }
#undef MK
#undef KSEL

  __syncthreads();
  for (int e = t; e < NCTR; e += 1024) fps_idx[b * NCTR + e] = fps_lds[e];
}

__global__ __launch_bounds__(256) void ballq_kernel(const float* __restrict__ xyz,
                                                    const int* __restrict__ fps_idx,
                                                    int* __restrict__ ball_idx) {
  const int gw = (blockIdx.x * 256 + threadIdx.x) >> 6;
  const int lane = threadIdx.x & 63;
  const int b = gw >> 10;
  const float* X = xyz + (size_t)b * 3 * NPTS;
  const float* Y = X + NPTS;
  const float* Z = X + 2 * NPTS;
  const int c = fps_idx[gw];
  const float cx = X[c], cy = Y[c], cz = Z[c];
  int* out = ball_idx + (size_t)gw * 32;
  const float R2 = 0.04f;

  int cnt = 0, first = -1;
  for (int base = 0; base < NPTS; base += 64) {
    const int j = base + lane;
    const float d = sq_dist(X[j], Y[j], Z[j], cx, cy, cz);
    const bool inb = !(d > R2);
    const unsigned long long m = __ballot(inb);
    if (first < 0 && m != 0ull) first = base + __ffsll(m) - 1;
    if (inb) {
      const int pos = cnt + __popcll(m & ((1ull << lane) - 1ull));
      if (pos < 32) out[pos] = j;
    }
    cnt += __popcll(m);
    if (cnt >= 32) break;
  }
  for (int k = cnt + lane; k < 32; k += 64) out[k] = first;
}

__global__ __launch_bounds__(256, 2) void mlp_kernel_np(
    const float* __restrict__ xyz, const float* __restrict__ points,
    const int* __restrict__ fps_idx, const int* __restrict__ ball_idx,
    const float* __restrict__ wt0, const float* __restrict__ b0,
    const float* __restrict__ wt1, const float* __restrict__ b1,
    const float* __restrict__ wt2, const float* __restrict__ b2,
    float* __restrict__ out) {
  const int bx = blockIdx.x, b = blockIdx.y, t = threadIdx.x;
  const int s = (bx & 7) * 128 + (bx >> 3);

  __shared__ float A1[64 * 36];
  __shared__ float A2[128 * 36];
  __shared__ float S[8704];
  __shared__ float bias_sh[256];
  __shared__ int jidx[32];
  __shared__ float ctr[3];

  const int g = b * NCTR + s;

  if (t < 32) jidx[t] = ball_idx[(size_t)g * 32 + t];
  if (t < 3) ctr[t] = xyz[((size_t)b * 3 + t) * NPTS + fps_idx[g]];
  float* A0 = S;
  float* Wt0 = S + 67 * 36;
  for (int e = t; e < 67 * 64; e += 256) {
    int c = e >> 6, o = e & 63;
    Wt0[c * 68 + o] = wt0[e];
  }
  if (t < 64) bias_sh[t] = b0[t];
  __syncthreads();

  for (int e = t; e < 67 * 32; e += 256) {
    int c = e >> 5, k = e & 31;
    int j = jidx[k];
    float v;
    if (c < 3)
      v = xyz[((size_t)b * 3 + c) * NPTS + j] - ctr[c];
    else
      v = points[((size_t)b * 64 + (c - 3)) * NPTS + j];
    A0[c * 36 + k] = v;
  }
  __syncthreads();

  {
    const int o0 = (t & 31) * 2;
    const int k0 = (t >> 5) * 4;
    float acc[4][2] = {{0.f, 0.f}, {0.f, 0.f}, {0.f, 0.f}, {0.f, 0.f}};
    for (int c = 0; c < 67; ++c) {
      const float4 a = *(const float4*)(A0 + c * 36 + k0);
      const float2 wv = *(const float2*)(Wt0 + c * 68 + o0);
      acc[0][0] = fmaf(a.x, wv.x, acc[0][0]);
      acc[1][0] = fmaf(a.y, wv.x, acc[1][0]);
      acc[2][0] = fmaf(a.z, wv.x, acc[2][0]);
      acc[3][0] = fmaf(a.w, wv.x, acc[3][0]);
      acc[0][1] = fmaf(a.x, wv.y, acc[0][1]);
      acc[1][1] = fmaf(a.y, wv.y, acc[1][1]);
      acc[2][1] = fmaf(a.z, wv.y, acc[2][1]);
      acc[3][1] = fmaf(a.w, wv.y, acc[3][1]);
    }
#pragma unroll
    for (int i = 0; i < 2; ++i) {
      const float bb = bias_sh[o0 + i];
      float4 r;
      r.x = silu_f(acc[0][i] + bb);
      r.y = silu_f(acc[1][i] + bb);
      r.z = silu_f(acc[2][i] + bb);
      r.w = silu_f(acc[3][i] + bb);
      *(float4*)(A1 + (o0 + i) * 36 + k0) = r;
    }
  }
  __syncthreads();

  float* Wt1 = S;
  for (int e = t; e < 128 * 64; e += 256) {
    int c = e >> 7, o = e & 127;
    Wt1[c * 132 + o] = wt1[e];
  }
  if (t < 128) bias_sh[t] = b1[t];
  __syncthreads();

  {
    const int o0 = (t & 31) * 4;
    const int k0 = (t >> 5) * 4;
    float acc[4][4];
#pragma unroll
    for (int kk = 0; kk < 4; ++kk)
#pragma unroll
      for (int oo = 0; oo < 4; ++oo) acc[kk][oo] = 0.f;
    for (int c = 0; c < 64; ++c) {
      const float4 a = *(const float4*)(A1 + c * 36 + k0);
      const float4 w = *(const float4*)(Wt1 + c * 132 + o0);
      const float av[4] = {a.x, a.y, a.z, a.w};
      const float wv[4] = {w.x, w.y, w.z, w.w};
#pragma unroll
      for (int kk = 0; kk < 4; ++kk)
#pragma unroll
        for (int oo = 0; oo < 4; ++oo)
          acc[kk][oo] = fmaf(av[kk], wv[oo], acc[kk][oo]);
    }
#pragma unroll
    for (int oo = 0; oo < 4; ++oo) {
      const float bb = bias_sh[o0 + oo];
      float4 r;
      r.x = silu_f(acc[0][oo] + bb);
      r.y = silu_f(acc[1][oo] + bb);
      r.z = silu_f(acc[2][oo] + bb);
      r.w = silu_f(acc[3][oo] + bb);
      *(float4*)(A2 + (o0 + oo) * 36 + k0) = r;
    }
  }
  __syncthreads();

  float* Wt2 = S;
  float* P = A1;
  const int o0 = (t & 31) * 2;
  const int k0 = (t >> 5) * 4;
  const int kg = t >> 5;
  for (int chunk = 0; chunk < 4; ++chunk) {
    for (int e = t; e < 64 * 128; e += 256) {
      int c = e >> 6, o = e & 63;
      Wt2[c * 68 + o] = wt2[c * 256 + chunk * 64 + o];
    }
    if (t < 64) bias_sh[t] = b2[chunk * 64 + t];
    __syncthreads();

    float acc[4][2] = {{0.f, 0.f}, {0.f, 0.f}, {0.f, 0.f}, {0.f, 0.f}};
    for (int c = 0; c < 128; ++c) {
      const float4 a = *(const float4*)(A2 + c * 36 + k0);
      const float2 wv = *(const float2*)(Wt2 + c * 68 + o0);
      acc[0][0] = fmaf(a.x, wv.x, acc[0][0]);
      acc[1][0] = fmaf(a.y, wv.x, acc[1][0]);
      acc[2][0] = fmaf(a.z, wv.x, acc[2][0]);
      acc[3][0] = fmaf(a.w, wv.x, acc[3][0]);
      acc[0][1] = fmaf(a.x, wv.y, acc[0][1]);
      acc[1][1] = fmaf(a.y, wv.y, acc[1][1]);
      acc[2][1] = fmaf(a.z, wv.y, acc[2][1]);
      acc[3][1] = fmaf(a.w, wv.y, acc[3][1]);
    }
#pragma unroll
    for (int i = 0; i < 2; ++i) {
      const float bb = bias_sh[o0 + i];
      float sum = silu_f(acc[0][i] + bb) + silu_f(acc[1][i] + bb) +
                  silu_f(acc[2][i] + bb) + silu_f(acc[3][i] + bb);
      P[(o0 + i) * 9 + kg] = sum;
    }
    __syncthreads();
    if (t < 64) {
      float tot = 0.f;
#pragma unroll
      for (int q = 0; q < 8; ++q) tot += P[t * 9 + q];
      out[((size_t)b * 256 + chunk * 64 + t) * NCTR + s] = tot * (1.0f / 32.0f);
    }
    __syncthreads();
  }
}

extern "C" void kernel_launch(void* const* d_in, const int* in_sizes, int n_in,
                              void* d_out, int out_size, void* d_ws, size_t ws_size,
                              hipStream_t stream) {
  const float* xyz = (const float*)d_in[0];
  const float* points = (const float*)d_in[1];
  const float* w0 = (const float*)d_in[2];
  const float* b0 = (const float*)d_in[3];
  const float* w1 = (const float*)d_in[4];
  const float* b1 = (const float*)d_in[5];
  const float* w2 = (const float*)d_in[6];
  const float* b2 = (const float*)d_in[7];
  float* out = (float*)d_out;

  int* fps = (int*)d_ws;                       // 8K ints
  int* bidx = (int*)d_ws + 8192;               // 256K ints (fallback only)
  u32* progress = (u32*)bidx;                  // first 8 u32 (coop path only)
  float* wt0 = (float*)d_ws + 270336;          // 67*64
  float* wt1 = wt0 + 67 * 64;                  // 64*128
  float* wt2 = wt1 + 64 * 128;                 // 128*256
  float* sxg = (float*)d_ws + 315584;          // 8*16384 sorted x
  float* syg = sxg + BATCH * NPTS;             // sorted y
  float* szg = syg + BATCH * NPTS;             // sorted z
  int* sog = (int*)(szg + BATCH * NPTS);       // sorted orig idx
  float* points_t = (float*)d_ws + 839872;     // [B][N][64] = 32 MB
  const size_t ws_need = ((size_t)839872 + (size_t)BATCH * NPTS * 64) * 4;

  transpose_w_kernel<<<64, 256, 0, stream>>>(w0, w1, w2, wt0, wt1, wt2, progress);
  sort_kernel<<<BATCH, 1024, 0, stream>>>(xyz, sxg, syg, szg, sog);

  const bool use_pt = ws_size >= ws_need;
  if (use_pt) {
    transpose_p_kernel<<<dim3(NPTS / 64, BATCH), 256, 0, stream>>>(points,
                                                                   points_t);
    void* args[] = {(void*)&xyz, (void*)&points_t, (void*)&sxg, (void*)&syg,
                    (void*)&szg, (void*)&sog, (void*)&fps, (void*)&progress,
                    (void*)&wt0, (void*)&b0, (void*)&wt1, (void*)&b1,
                    (void*)&wt2, (void*)&b2, (void*)&out};
    hipError_t err = hipLaunchCooperativeKernel(
        reinterpret_cast<const void*>(mega_kernel), dim3(GRID_MEGA), dim3(1024),
        args, 0, stream);
    if (err == hipSuccess) return;
  }
  // fallback: measured serial pipeline
  fps_kernel<<<BATCH, 1024, 0, stream>>>(xyz, sxg, syg, szg, sog, fps);
  ballq_kernel<<<2048, 256, 0, stream>>>(xyz, fps, bidx);
  mlp_kernel_np<<<dim3(NCTR, BATCH), 256, 0, stream>>>(xyz, points, fps, bidx,
                                                       wt0, b0, wt1, b1, wt2,
                                                       b2, out);
}